// Round 1
// baseline (602.183 us; speedup 1.0000x reference)
//
#include <hip/hip_runtime.h>
#include <math.h>

typedef __attribute__((ext_vector_type(8))) short bf16x8;
typedef __attribute__((ext_vector_type(4))) float f32x4;

__device__ inline unsigned short f2bf(float x){
  unsigned u = __builtin_bit_cast(unsigned, x);
  u = (u + 0x7FFFu + ((u >> 16) & 1u)) >> 16;
  return (unsigned short)u;
}

#define KVLEN 4096
#define QLEN  128
#define NH    32
#define NKVH  8
#define HD    128
#define HIDD  4096

// ---------------- prep: dtype detection + per-batch RoPE tables ----------------
__global__ void prep_kernel(const int* __restrict__ pos32,
                            const unsigned int* __restrict__ mask32,
                            float* __restrict__ costab,
                            float* __restrict__ sintab,
                            int* __restrict__ flags){
  int tid = threadIdx.x;
  if (tid == 0){
    // mask elem size: u8 bools have nonzero bytes at offsets %4 != 0
    int m8 = 0;
    for (int i = 0; i < 64; ++i)
      if (mask32[i] & 0xFFFFFF00u){ m8 = 1; break; }
    flags[0] = m8;
  }
  int b = tid >> 6, j = tid & 63;          // 4 batches x 64 freqs
  // position dtype: if int64 (LE), the high word of element 4095 is 0.
  bool pos64 = (pos32[2*4095 + 1] == 0);
  long long mpos;
  if (pos64) mpos = ((const long long*)pos32)[(size_t)b*KVLEN + KVLEN - 1];
  else       mpos = (long long)pos32[(size_t)b*KVLEN + KVLEN - 1];
  // rows are sorted ascending -> last element is the max (what argmax picks)
  double inv = pow(10000.0, -((double)j) / 64.0);
  double ang = (double)mpos * inv;
  costab[b*64 + j] = (float)cos(ang);
  sintab[b*64 + j] = (float)sin(ang);
}

// ---------------- GEMM: C[M,N] = A[M,K](f32) * B[K,N](f32), bf16 MFMA ----------------
// BM=64 BN=128 BK=32, 256 threads (4 waves, 2x2), grid (N/128, M/64)
__global__ __launch_bounds__(256) void gemm_kernel(const float* __restrict__ A,
                                                   const float* __restrict__ B,
                                                   float* __restrict__ C,
                                                   int N, int K){
  __shared__ alignas(16) unsigned short Alds[64][40];    // [m][k], pad 32->40
  __shared__ alignas(16) unsigned short Blds[128][40];   // [n][k] (transposed)
  int tid = threadIdx.x;
  int lane = tid & 63;
  int w = tid >> 6, wm = w >> 1, wn = w & 1;
  int l16 = lane & 15, lk4 = lane >> 4;
  int bm = blockIdx.y, bn = blockIdx.x;

  f32x4 acc[2][4] = {};

  int ar = tid >> 2, ac8 = (tid & 3) * 8;                 // A: 64 rows x 4 col-groups
  const float* Ap = A + (size_t)(bm*64 + ar) * K + ac8;
  int bcol = tid & 127, bkh = (tid >> 7) * 16;            // B: 128 cols x 2 k-halves
  const float* Bp = B + (size_t)bkh * N + (size_t)bn * 128 + bcol;

  for (int k0 = 0; k0 < K; k0 += 32){
    // stage A (row-vector loads)
    {
      f32x4 a0 = *(const f32x4*)(Ap + k0);
      f32x4 a1 = *(const f32x4*)(Ap + k0 + 4);
      bf16x8 av;
#pragma unroll
      for (int t = 0; t < 4; ++t){ av[t] = (short)f2bf(a0[t]); av[t+4] = (short)f2bf(a1[t]); }
      *(bf16x8*)&Alds[ar][ac8] = av;
    }
    // stage B (column loads, coalesced across lanes), store transposed [n][k]
    {
      const float* bp = Bp + (size_t)k0 * N;
      bf16x8 bv0, bv1;
#pragma unroll
      for (int i = 0; i < 8; ++i) bv0[i] = (short)f2bf(bp[(size_t)i * N]);
#pragma unroll
      for (int i = 0; i < 8; ++i) bv1[i] = (short)f2bf(bp[(size_t)(i+8) * N]);
      *(bf16x8*)&Blds[bcol][bkh]     = bv0;
      *(bf16x8*)&Blds[bcol][bkh + 8] = bv1;
    }
    __syncthreads();
    bf16x8 af[2], bfr[4];
#pragma unroll
    for (int i = 0; i < 2; ++i) af[i]  = *(const bf16x8*)&Alds[wm*32 + i*16 + l16][lk4*8];
#pragma unroll
    for (int j = 0; j < 4; ++j) bfr[j] = *(const bf16x8*)&Blds[wn*64 + j*16 + l16][lk4*8];
#pragma unroll
    for (int i = 0; i < 2; ++i)
#pragma unroll
      for (int j = 0; j < 4; ++j)
        acc[i][j] = __builtin_amdgcn_mfma_f32_16x16x32_bf16(af[i], bfr[j], acc[i][j], 0, 0, 0);
    __syncthreads();
  }
#pragma unroll
  for (int i = 0; i < 2; ++i)
#pragma unroll
    for (int j = 0; j < 4; ++j)
#pragma unroll
      for (int r = 0; r < 4; ++r){
        int row = bm*64 + wm*32 + i*16 + lk4*4 + r;
        int col = bn*128 + wn*64 + j*16 + l16;
        C[(size_t)row * N + col] = acc[i][j][r];
      }
}

// ---------------- RoPE + scale + bf16 cast: qpre[512,4096] -> qbf[b][h][ql][d] ----------------
__global__ __launch_bounds__(256) void rope_kernel(const float* __restrict__ qpre,
                                                   const float* __restrict__ costab,
                                                   const float* __restrict__ sintab,
                                                   unsigned short* __restrict__ qbf){
  int idx = blockIdx.x * 256 + threadIdx.x;   // 512*32*64 threads
  int half = idx & 63;
  int h    = (idx >> 6) & 31;
  int row  = idx >> 11;                       // 0..511 = b*128+ql
  int b  = row >> 7;
  int ql = row & 127;
  float c = costab[b*64 + half];
  float s = sintab[b*64 + half];
  size_t base = (size_t)row * HIDD + (size_t)h * HD;
  float x1 = qpre[base + half];
  float x2 = qpre[base + half + 64];
  const float scale = 0.08838834764831845f;   // 1/sqrt(128)
  float y1 = (x1 * c - x2 * s) * scale;
  float y2 = (x2 * c + x1 * s) * scale;
  size_t ob = ((size_t)(b*NH + h) * QLEN + ql) * HD;
  qbf[ob + half]      = f2bf(y1);
  qbf[ob + half + 64] = f2bf(y2);
}

// ---------------- flash attention: grid (qb=2, h=32, b=4), 256 threads ----------------
__global__ __launch_bounds__(256) void attn_kernel(const unsigned short* __restrict__ Q,
                                                   const float* __restrict__ Kg,
                                                   const float* __restrict__ Vg,
                                                   const void* __restrict__ mask,
                                                   const int* __restrict__ flags,
                                                   float* __restrict__ O){
  __shared__ alignas(16) unsigned short Klds[64*128];   // [kv][d], xor-swizzled
  __shared__ alignas(16) unsigned short Vlds[128*64];   // [d][kv] transposed, swizzled
  __shared__ alignas(16) unsigned short Plds[4][16*64]; // per-wave P, swizzled
  int qb = blockIdx.x, h = blockIdx.y, b = blockIdx.z;
  int kvh = h >> 2;                                     // GQA: 4 q-heads per kv-head
  int tid = threadIdx.x, lane = tid & 63, w = tid >> 6;
  int l16 = lane & 15, lk4 = lane >> 4;
  bool m8 = (flags[0] != 0);
  const unsigned char* mask8p = (const unsigned char*)mask;
  const int* mask32p = (const int*)mask;

  // Q fragments stay in registers for the whole block
  bf16x8 qf[4];
  {
    const unsigned short* qp = Q + (((size_t)(b*NH + h) * QLEN) + qb*64 + w*16 + l16) * HD;
#pragma unroll
    for (int ks = 0; ks < 4; ++ks)
      qf[ks] = *(const bf16x8*)(qp + ks*32 + lk4*8);
  }
  f32x4 acc_o[8] = {};
  float mrun[4], lrun[4];
#pragma unroll
  for (int r = 0; r < 4; ++r){ mrun[r] = -1e30f; lrun[r] = 0.f; }

  const float* Kbase = Kg + (size_t)(b*NKVH + kvh) * KVLEN * HD;
  const float* Vbase = Vg + (size_t)(b*NKVH + kvh) * KVLEN * HD;
  size_t mbase = ((size_t)(b*QLEN + qb*64 + w*16 + lk4*4)) * KVLEN;

  int kr = tid >> 2;              // K stage: row 0..63
  int kc = (tid & 3) * 8;         // K stage: col group base (stride 32 over i)
  int vd = tid & 127;             // V stage: d column
  int vk = (tid >> 7) * 32;       // V stage: kv base

  for (int kv0 = 0; kv0 < KVLEN; kv0 += 64){
    // ---- stage K tile [64][128] fp32 -> bf16 LDS (swizzled) ----
    {
      const float* kp = Kbase + (size_t)(kv0 + kr) * HD;
#pragma unroll
      for (int i = 0; i < 4; ++i){
        int d0 = kc + i*32;
        f32x4 x0 = *(const f32x4*)(kp + d0);
        f32x4 x1 = *(const f32x4*)(kp + d0 + 4);
        bf16x8 s;
#pragma unroll
        for (int t = 0; t < 4; ++t){ s[t] = (short)f2bf(x0[t]); s[t+4] = (short)f2bf(x1[t]); }
        unsigned byteoff = ((unsigned)kr*256u + (unsigned)d0*2u) ^ (((unsigned)kr & 7u) << 4);
        *(bf16x8*)((char*)Klds + byteoff) = s;
      }
    }
    // ---- stage V tile transposed [d][kv] (swizzled) ----
    {
      const float* vp = Vbase + (size_t)(kv0 + vk) * HD + vd;
#pragma unroll
      for (int i8 = 0; i8 < 4; ++i8){
        bf16x8 s;
#pragma unroll
        for (int t = 0; t < 8; ++t) s[t] = (short)f2bf(vp[(size_t)(i8*8 + t) * HD]);
        unsigned byteoff = ((unsigned)vd*128u + (unsigned)(vk + i8*8)*2u) ^ (((unsigned)vd & 7u) << 4);
        *(bf16x8*)((char*)Vlds + byteoff) = s;
      }
    }
    __syncthreads();

    // ---- S = Q K^T ----
    f32x4 sacc[4] = {};
#pragma unroll
    for (int nf = 0; nf < 4; ++nf){
      int krow = nf*16 + l16;
#pragma unroll
      for (int ks = 0; ks < 4; ++ks){
        unsigned byteoff = ((unsigned)krow*256u + (unsigned)(ks*32 + lk4*8)*2u) ^ (((unsigned)krow & 7u) << 4);
        bf16x8 kf = *(const bf16x8*)((const char*)Klds + byteoff);
        sacc[nf] = __builtin_amdgcn_mfma_f32_16x16x32_bf16(qf[ks], kf, sacc[nf], 0, 0, 0);
      }
    }

    // ---- mask + online softmax (rows tracked per (lk4, r)) ----
    float p[4][4];
    float pmax[4];
#pragma unroll
    for (int r = 0; r < 4; ++r) pmax[r] = -1e30f;
#pragma unroll
    for (int nf = 0; nf < 4; ++nf)
#pragma unroll
      for (int r = 0; r < 4; ++r){
        size_t mi = mbase + (size_t)r*KVLEN + (size_t)(kv0 + nf*16 + l16);
        bool mk = m8 ? (mask8p[mi] != 0) : (mask32p[mi] != 0);
        float sv = mk ? -10000.f : sacc[nf][r];
        p[nf][r] = sv;
        pmax[r] = fmaxf(pmax[r], sv);
      }
#pragma unroll
    for (int r = 0; r < 4; ++r){
#pragma unroll
      for (int mb = 1; mb < 16; mb <<= 1)
        pmax[r] = fmaxf(pmax[r], __shfl_xor(pmax[r], mb, 64));
    }
    float psum[4];
#pragma unroll
    for (int r = 0; r < 4; ++r){
      float mnew = fmaxf(mrun[r], pmax[r]);
      float corr = __expf(mrun[r] - mnew);
      mrun[r] = mnew;
      lrun[r] *= corr;
#pragma unroll
      for (int nf8 = 0; nf8 < 8; ++nf8) acc_o[nf8][r] *= corr;
      float ps = 0.f;
#pragma unroll
      for (int nf = 0; nf < 4; ++nf){
        float e = __expf(p[nf][r] - mnew);
        p[nf][r] = e;
        ps += e;
      }
      psum[r] = ps;
    }
#pragma unroll
    for (int r = 0; r < 4; ++r){
#pragma unroll
      for (int mb = 1; mb < 16; mb <<= 1)
        psum[r] += __shfl_xor(psum[r], mb, 64);
      lrun[r] += psum[r];
    }

    // ---- P -> per-wave LDS (transpose C-layout -> A-layout) ----
    unsigned short* pw = &Plds[w][0];
#pragma unroll
    for (int nf = 0; nf < 4; ++nf)
#pragma unroll
      for (int r = 0; r < 4; ++r){
        unsigned prow = (unsigned)(lk4*4 + r);
        unsigned pcol = (unsigned)(nf*16 + l16);
        unsigned byteoff = (prow*128u + pcol*2u) ^ ((prow & 7u) << 4);
        *(unsigned short*)((char*)pw + byteoff) = f2bf(p[nf][r]);
      }
    __syncthreads();

    // ---- O += P V ----
    bf16x8 pf[2];
#pragma unroll
    for (int ks2 = 0; ks2 < 2; ++ks2){
      unsigned byteoff = ((unsigned)l16*128u + (unsigned)(ks2*32 + lk4*8)*2u) ^ (((unsigned)l16 & 7u) << 4);
      pf[ks2] = *(const bf16x8*)((const char*)pw + byteoff);
    }
#pragma unroll
    for (int nf8 = 0; nf8 < 8; ++nf8){
      unsigned vrow = (unsigned)(nf8*16 + l16);
#pragma unroll
      for (int ks2 = 0; ks2 < 2; ++ks2){
        unsigned byteoff = (vrow*128u + (unsigned)(ks2*32 + lk4*8)*2u) ^ ((vrow & 7u) << 4);
        bf16x8 vf = *(const bf16x8*)((const char*)Vlds + byteoff);
        acc_o[nf8] = __builtin_amdgcn_mfma_f32_16x16x32_bf16(pf[ks2], vf, acc_o[nf8], 0, 0, 0);
      }
    }
    __syncthreads();
  }

  // ---- epilogue: O[b*128+ql][h*128+d] = acc/l ----
#pragma unroll
  for (int nf8 = 0; nf8 < 8; ++nf8)
#pragma unroll
    for (int r = 0; r < 4; ++r){
      int row = qb*64 + w*16 + lk4*4 + r;
      int col = h*HD + nf8*16 + l16;
      O[(size_t)(b*QLEN + row) * HIDD + col] = acc_o[nf8][r] / lrun[r];
    }
}

// ---------------- launch ----------------
extern "C" void kernel_launch(void* const* d_in, const int* in_sizes, int n_in,
                              void* d_out, int out_size, void* d_ws, size_t ws_size,
                              hipStream_t stream){
  (void)in_sizes; (void)n_in; (void)out_size; (void)ws_size;
  const float* hidden = (const float*)d_in[0];
  const float* kst    = (const float*)d_in[1];
  const float* vst    = (const float*)d_in[2];
  const float* wq     = (const float*)d_in[3];
  const float* wo     = (const float*)d_in[4];
  const void*  pos    = d_in[5];
  const void*  mask   = d_in[6];
  float* out = (float*)d_out;

  char* ws = (char*)d_ws;
  float* qpre = (float*)ws;                                  // 8 MB, reused as attn-out
  unsigned short* qbf = (unsigned short*)(ws + (8u << 20));  // 4 MB
  float* costab = (float*)(ws + (12u << 20));                // 4*64 f32
  float* sintab = costab + 256;
  int*   flags  = (int*)(sintab + 256);
  float* attno = qpre;                                       // qpre dead after rope

  prep_kernel<<<1, 256, 0, stream>>>((const int*)pos, (const unsigned int*)mask,
                                     costab, sintab, flags);
  gemm_kernel<<<dim3(32, 8), 256, 0, stream>>>(hidden, wq, qpre, HIDD, HIDD);
  rope_kernel<<<4096, 256, 0, stream>>>(qpre, costab, sintab, qbf);
  attn_kernel<<<dim3(2, 32, 4), 256, 0, stream>>>(qbf, kst, vst, mask, flags, attno);
  gemm_kernel<<<dim3(32, 8), 256, 0, stream>>>(attno, wo, out, HIDD, HIDD);
}

// Round 2
// 561.624 us; speedup vs baseline: 1.0722x; 1.0722x over previous
//
#include <hip/hip_runtime.h>
#include <math.h>

typedef __attribute__((ext_vector_type(8))) short bf16x8;
typedef __attribute__((ext_vector_type(4))) float f32x4;

__device__ inline unsigned short f2bf(float x){
  unsigned u = __builtin_bit_cast(unsigned, x);
  u = (u + 0x7FFFu + ((u >> 16) & 1u)) >> 16;
  return (unsigned short)u;
}

#define KVLEN 4096
#define QLEN  128
#define NH    32
#define NKVH  8
#define HD    128
#define HIDD  4096
#define NSPLIT 4
#define KVCHUNK (KVLEN / NSPLIT)

// ---------------- prep: dtype detection + per-batch RoPE tables ----------------
__global__ void prep_kernel(const int* __restrict__ pos32,
                            const unsigned int* __restrict__ mask32,
                            float* __restrict__ costab,
                            float* __restrict__ sintab,
                            int* __restrict__ flags){
  int tid = threadIdx.x;
  if (tid == 0){
    // mask elem size: u8 bools have nonzero bytes at offsets %4 != 0
    int m8 = 0;
    for (int i = 0; i < 64; ++i)
      if (mask32[i] & 0xFFFFFF00u){ m8 = 1; break; }
    flags[0] = m8;
  }
  int b = tid >> 6, j = tid & 63;          // 4 batches x 64 freqs
  // position dtype: if int64 (LE), the high word of element 4095 is 0.
  bool pos64 = (pos32[2*4095 + 1] == 0);
  long long mpos;
  if (pos64) mpos = ((const long long*)pos32)[(size_t)b*KVLEN + KVLEN - 1];
  else       mpos = (long long)pos32[(size_t)b*KVLEN + KVLEN - 1];
  // rows are sorted ascending -> last element is the max (what argmax picks)
  double inv = pow(10000.0, -((double)j) / 64.0);
  double ang = (double)mpos * inv;
  costab[b*64 + j] = (float)cos(ang);
  sintab[b*64 + j] = (float)sin(ang);
}

// ---------------- mask pack: bool[B,1,QL,KVL] -> u64 bitmask ----------------
__global__ __launch_bounds__(256) void maskpack_kernel(const void* __restrict__ mask,
                                                       const int* __restrict__ flags,
                                                       unsigned long long* __restrict__ bits){
  int idx = blockIdx.x * 256 + threadIdx.x;     // 4*128*4096 threads, kv fastest
  bool m8 = (flags[0] != 0);
  bool v = m8 ? (((const unsigned char*)mask)[idx] != 0)
              : (((const int*)mask)[idx] != 0);
  unsigned long long bal = __ballot(v);
  if ((threadIdx.x & 63) == 0) bits[idx >> 6] = bal;
}

// ---------------- GEMM: C[M,N] = A[M,K](f32) * B[K,N](f32), bf16 MFMA ----------------
// BM=64 BN=128 BK=32, 256 threads (4 waves, 2x2), grid (N/128, M/64)
__global__ __launch_bounds__(256) void gemm_kernel(const float* __restrict__ A,
                                                   const float* __restrict__ B,
                                                   float* __restrict__ C,
                                                   int N, int K){
  __shared__ alignas(16) unsigned short Alds[64][40];    // [m][k], pad 32->40
  __shared__ alignas(16) unsigned short Blds[128][40];   // [n][k] (transposed)
  int tid = threadIdx.x;
  int lane = tid & 63;
  int w = tid >> 6, wm = w >> 1, wn = w & 1;
  int l16 = lane & 15, lk4 = lane >> 4;
  int bm = blockIdx.y, bn = blockIdx.x;

  f32x4 acc[2][4] = {};

  int ar = tid >> 2, ac8 = (tid & 3) * 8;                 // A: 64 rows x 4 col-groups
  const float* Ap = A + (size_t)(bm*64 + ar) * K + ac8;
  int bcol = tid & 127, bkh = (tid >> 7) * 16;            // B: 128 cols x 2 k-halves
  const float* Bp = B + (size_t)bkh * N + (size_t)bn * 128 + bcol;

  for (int k0 = 0; k0 < K; k0 += 32){
    // stage A (row-vector loads)
    {
      f32x4 a0 = *(const f32x4*)(Ap + k0);
      f32x4 a1 = *(const f32x4*)(Ap + k0 + 4);
      bf16x8 av;
#pragma unroll
      for (int t = 0; t < 4; ++t){ av[t] = (short)f2bf(a0[t]); av[t+4] = (short)f2bf(a1[t]); }
      *(bf16x8*)&Alds[ar][ac8] = av;
    }
    // stage B (column loads, coalesced across lanes), store transposed [n][k]
    {
      const float* bp = Bp + (size_t)k0 * N;
      bf16x8 bv0, bv1;
#pragma unroll
      for (int i = 0; i < 8; ++i) bv0[i] = (short)f2bf(bp[(size_t)i * N]);
#pragma unroll
      for (int i = 0; i < 8; ++i) bv1[i] = (short)f2bf(bp[(size_t)(i+8) * N]);
      *(bf16x8*)&Blds[bcol][bkh]     = bv0;
      *(bf16x8*)&Blds[bcol][bkh + 8] = bv1;
    }
    __syncthreads();
    bf16x8 af[2], bfr[4];
#pragma unroll
    for (int i = 0; i < 2; ++i) af[i]  = *(const bf16x8*)&Alds[wm*32 + i*16 + l16][lk4*8];
#pragma unroll
    for (int j = 0; j < 4; ++j) bfr[j] = *(const bf16x8*)&Blds[wn*64 + j*16 + l16][lk4*8];
#pragma unroll
    for (int i = 0; i < 2; ++i)
#pragma unroll
      for (int j = 0; j < 4; ++j)
        acc[i][j] = __builtin_amdgcn_mfma_f32_16x16x32_bf16(af[i], bfr[j], acc[i][j], 0, 0, 0);
    __syncthreads();
  }
#pragma unroll
  for (int i = 0; i < 2; ++i)
#pragma unroll
    for (int j = 0; j < 4; ++j)
#pragma unroll
      for (int r = 0; r < 4; ++r){
        int row = bm*64 + wm*32 + i*16 + lk4*4 + r;
        int col = bn*128 + wn*64 + j*16 + l16;
        C[(size_t)row * N + col] = acc[i][j][r];
      }
}

// ---------------- RoPE + scale + bf16 cast: qpre[512,4096] -> qbf[b][h][ql][d] ----------------
__global__ __launch_bounds__(256) void rope_kernel(const float* __restrict__ qpre,
                                                   const float* __restrict__ costab,
                                                   const float* __restrict__ sintab,
                                                   unsigned short* __restrict__ qbf){
  int idx = blockIdx.x * 256 + threadIdx.x;   // 512*32*64 threads
  int half = idx & 63;
  int h    = (idx >> 6) & 31;
  int row  = idx >> 11;                       // 0..511 = b*128+ql
  int b  = row >> 7;
  int ql = row & 127;
  float c = costab[b*64 + half];
  float s = sintab[b*64 + half];
  size_t base = (size_t)row * HIDD + (size_t)h * HD;
  float x1 = qpre[base + half];
  float x2 = qpre[base + half + 64];
  const float scale = 0.08838834764831845f;   // 1/sqrt(128)
  float y1 = (x1 * c - x2 * s) * scale;
  float y2 = (x2 * c + x1 * s) * scale;
  size_t ob = ((size_t)(b*NH + h) * QLEN + ql) * HD;
  qbf[ob + half]      = f2bf(y1);
  qbf[ob + half + 64] = f2bf(y2);
}

// ---------------- flash attention, KV-split: 1024 blocks, 256 threads ----------------
// block decode: XCD-grouped so the 8 blocks sharing a (b,kvh,s) chunk land on one XCD.
__global__ __launch_bounds__(256, 4) void attn_kernel(const unsigned short* __restrict__ Q,
                                                      const float* __restrict__ Kg,
                                                      const float* __restrict__ Vg,
                                                      const unsigned long long* __restrict__ bits,
                                                      float* __restrict__ Opart,
                                                      float* __restrict__ Mpart,
                                                      float* __restrict__ Lpart){
  __shared__ alignas(16) unsigned short Klds[64*128];   // [kv][d], xor-swizzled
  __shared__ alignas(16) unsigned short Vlds[128*64];   // [d][kv] transposed, swizzled
  __shared__ alignas(16) unsigned short Plds[4][16*64]; // per-wave P, swizzled
  int bid = blockIdx.x;
  int j = (bid >> 3) & 7;
  int g = (bid & 7) | ((bid >> 6) << 3);        // group = (b,kvh,s), 8 sharers per group
  int s   = g & 3;
  int kvh = (g >> 2) & 7;
  int b   = g >> 5;
  int hg  = j >> 1, qb = j & 1;
  int h   = kvh * 4 + hg;                       // GQA: 4 q-heads per kv-head

  int tid = threadIdx.x, lane = tid & 63, w = tid >> 6;
  int l16 = lane & 15, lk4 = lane >> 4;

  // Q fragments stay in registers for the whole block
  bf16x8 qf[4];
  {
    const unsigned short* qp = Q + (((size_t)(b*NH + h) * QLEN) + qb*64 + w*16 + l16) * HD;
#pragma unroll
    for (int ks = 0; ks < 4; ++ks)
      qf[ks] = *(const bf16x8*)(qp + ks*32 + lk4*8);
  }
  f32x4 acc_o[8] = {};
  float mrun[4], lrun[4];
#pragma unroll
  for (int r = 0; r < 4; ++r){ mrun[r] = -1e30f; lrun[r] = 0.f; }

  const float* Kbase = Kg + (size_t)(b*NKVH + kvh) * KVLEN * HD;
  const float* Vbase = Vg + (size_t)(b*NKVH + kvh) * KVLEN * HD;
  // bitmask row base for each of this thread's 4 rows
  size_t bbase = ((size_t)(b*QLEN + qb*64 + w*16 + lk4*4)) << 6;   // *64 words/row

  int kr = tid >> 2;              // K stage: row 0..63
  int kc = (tid & 3) * 8;         // K stage: col group base (stride 32 over i)
  int vd = tid & 127;             // V stage: d column
  int vk = (tid >> 7) * 32;       // V stage: kv base

  const int kvbeg = s * KVCHUNK;
  for (int kv0 = kvbeg; kv0 < kvbeg + KVCHUNK; kv0 += 64){
    // ---- stage K tile [64][128] fp32 -> bf16 LDS (swizzled) ----
    {
      const float* kp = Kbase + (size_t)(kv0 + kr) * HD;
#pragma unroll
      for (int i = 0; i < 4; ++i){
        int d0 = kc + i*32;
        f32x4 x0 = *(const f32x4*)(kp + d0);
        f32x4 x1 = *(const f32x4*)(kp + d0 + 4);
        bf16x8 sv;
#pragma unroll
        for (int t = 0; t < 4; ++t){ sv[t] = (short)f2bf(x0[t]); sv[t+4] = (short)f2bf(x1[t]); }
        unsigned byteoff = ((unsigned)kr*256u + (unsigned)d0*2u) ^ (((unsigned)kr & 7u) << 4);
        *(bf16x8*)((char*)Klds + byteoff) = sv;
      }
    }
    // ---- stage V tile transposed [d][kv] (swizzled) ----
    {
      const float* vp = Vbase + (size_t)(kv0 + vk) * HD + vd;
#pragma unroll
      for (int i8 = 0; i8 < 4; ++i8){
        bf16x8 sv;
#pragma unroll
        for (int t = 0; t < 8; ++t) sv[t] = (short)f2bf(vp[(size_t)(i8*8 + t) * HD]);
        unsigned byteoff = ((unsigned)vd*128u + (unsigned)(vk + i8*8)*2u) ^ (((unsigned)vd & 7u) << 4);
        *(bf16x8*)((char*)Vlds + byteoff) = sv;
      }
    }
    __syncthreads();

    // ---- S = Q K^T ----
    f32x4 sacc[4] = {};
#pragma unroll
    for (int nf = 0; nf < 4; ++nf){
      int krow = nf*16 + l16;
#pragma unroll
      for (int ks = 0; ks < 4; ++ks){
        unsigned byteoff = ((unsigned)krow*256u + (unsigned)(ks*32 + lk4*8)*2u) ^ (((unsigned)krow & 7u) << 4);
        bf16x8 kf = *(const bf16x8*)((const char*)Klds + byteoff);
        sacc[nf] = __builtin_amdgcn_mfma_f32_16x16x32_bf16(qf[ks], kf, sacc[nf], 0, 0, 0);
      }
    }

    // ---- mask (bitmask words) + online softmax ----
    unsigned long long wrd[4];
#pragma unroll
    for (int r = 0; r < 4; ++r)
      wrd[r] = bits[bbase + (size_t)r*64 + (size_t)(kv0 >> 6)];

    float p[4][4];
    float pmax[4];
#pragma unroll
    for (int r = 0; r < 4; ++r) pmax[r] = -1e30f;
#pragma unroll
    for (int nf = 0; nf < 4; ++nf)
#pragma unroll
      for (int r = 0; r < 4; ++r){
        bool mk = (wrd[r] >> (nf*16 + l16)) & 1ull;
        float sv = mk ? -10000.f : sacc[nf][r];
        p[nf][r] = sv;
        pmax[r] = fmaxf(pmax[r], sv);
      }
#pragma unroll
    for (int r = 0; r < 4; ++r){
#pragma unroll
      for (int mb = 1; mb < 16; mb <<= 1)
        pmax[r] = fmaxf(pmax[r], __shfl_xor(pmax[r], mb, 64));
    }
    float psum[4];
#pragma unroll
    for (int r = 0; r < 4; ++r){
      float mnew = fmaxf(mrun[r], pmax[r]);
      float corr = __expf(mrun[r] - mnew);
      mrun[r] = mnew;
      lrun[r] *= corr;
#pragma unroll
      for (int nf8 = 0; nf8 < 8; ++nf8) acc_o[nf8][r] *= corr;
      float ps = 0.f;
#pragma unroll
      for (int nf = 0; nf < 4; ++nf){
        float e = __expf(p[nf][r] - mnew);
        p[nf][r] = e;
        ps += e;
      }
      psum[r] = ps;
    }
#pragma unroll
    for (int r = 0; r < 4; ++r){
#pragma unroll
      for (int mb = 1; mb < 16; mb <<= 1)
        psum[r] += __shfl_xor(psum[r], mb, 64);
      lrun[r] += psum[r];
    }

    // ---- P -> per-wave LDS (transpose C-layout -> A-layout) ----
    unsigned short* pw = &Plds[w][0];
#pragma unroll
    for (int nf = 0; nf < 4; ++nf)
#pragma unroll
      for (int r = 0; r < 4; ++r){
        unsigned prow = (unsigned)(lk4*4 + r);
        unsigned pcol = (unsigned)(nf*16 + l16);
        unsigned byteoff = (prow*128u + pcol*2u) ^ ((prow & 7u) << 4);
        *(unsigned short*)((char*)pw + byteoff) = f2bf(p[nf][r]);
      }
    // per-wave LDS only: DS ops from one wave are in-order; fence the compiler,
    // drain lgkm so reads below see the writes. No cross-wave hazard -> no barrier.
    __builtin_amdgcn_sched_barrier(0);
    asm volatile("s_waitcnt lgkmcnt(0)" ::: "memory");
    __builtin_amdgcn_sched_barrier(0);

    // ---- O += P V ----
    bf16x8 pf[2];
#pragma unroll
    for (int ks2 = 0; ks2 < 2; ++ks2){
      unsigned byteoff = ((unsigned)l16*128u + (unsigned)(ks2*32 + lk4*8)*2u) ^ (((unsigned)l16 & 7u) << 4);
      pf[ks2] = *(const bf16x8*)((const char*)pw + byteoff);
    }
#pragma unroll
    for (int nf8 = 0; nf8 < 8; ++nf8){
      unsigned vrow = (unsigned)(nf8*16 + l16);
#pragma unroll
      for (int ks2 = 0; ks2 < 2; ++ks2){
        unsigned byteoff = (vrow*128u + (unsigned)(ks2*32 + lk4*8)*2u) ^ ((vrow & 7u) << 4);
        bf16x8 vf = *(const bf16x8*)((const char*)Vlds + byteoff);
        acc_o[nf8] = __builtin_amdgcn_mfma_f32_16x16x32_bf16(pf[ks2], vf, acc_o[nf8], 0, 0, 0);
      }
    }
    __syncthreads();
  }

  // ---- epilogue: unnormalized partials + (m,l) ----
  // Opart layout [s][b][h][ql][d]; Mpart/Lpart layout [s][b][h][ql]
  size_t rowbase = ((size_t)(s*4 + b) * NH + h) * QLEN + qb*64 + w*16 + lk4*4;
#pragma unroll
  for (int nf8 = 0; nf8 < 8; ++nf8)
#pragma unroll
    for (int r = 0; r < 4; ++r){
      int col = nf8*16 + l16;
      Opart[(rowbase + r) * HD + col] = acc_o[nf8][r];
    }
  if (l16 == 0){
#pragma unroll
    for (int r = 0; r < 4; ++r){
      Mpart[rowbase + r] = mrun[r];
      Lpart[rowbase + r] = lrun[r];
    }
  }
}

// ---------------- combine: merge NSPLIT partials -> attno[b*128+ql][h*128+d] ----------------
__global__ __launch_bounds__(256) void combine_kernel(const float* __restrict__ Opart,
                                                      const float* __restrict__ Mpart,
                                                      const float* __restrict__ Lpart,
                                                      float* __restrict__ attno){
  int idx = blockIdx.x * 256 + threadIdx.x;     // B*H*QL*D = 2,097,152
  int d = idx & 127;
  int row = idx >> 7;                           // (b*32+h)*128 + ql
  const int RS = 4 * NH * QLEN;                 // rows per split = 16384
  float m[NSPLIT];
#pragma unroll
  for (int s = 0; s < NSPLIT; ++s) m[s] = Mpart[(size_t)s*RS + row];
  float M = fmaxf(fmaxf(m[0], m[1]), fmaxf(m[2], m[3]));
  float L = 0.f, num = 0.f;
#pragma unroll
  for (int s = 0; s < NSPLIT; ++s){
    float ws = __expf(m[s] - M);
    L   += ws * Lpart[(size_t)s*RS + row];
    num += ws * Opart[((size_t)s*RS + row) * HD + d];
  }
  int ql = row & 127, h = (row >> 7) & 31, b = row >> 12;
  attno[((size_t)(b*QLEN + ql)) * HIDD + h*HD + d] = num / L;
}

// ---------------- launch ----------------
extern "C" void kernel_launch(void* const* d_in, const int* in_sizes, int n_in,
                              void* d_out, int out_size, void* d_ws, size_t ws_size,
                              hipStream_t stream){
  (void)in_sizes; (void)n_in; (void)out_size; (void)ws_size;
  const float* hidden = (const float*)d_in[0];
  const float* kst    = (const float*)d_in[1];
  const float* vst    = (const float*)d_in[2];
  const float* wq     = (const float*)d_in[3];
  const float* wo     = (const float*)d_in[4];
  const void*  pos    = d_in[5];
  const void*  mask   = d_in[6];
  float* out = (float*)d_out;

  char* ws = (char*)d_ws;
  float* Opart = (float*)ws;                                    // 32 MiB
  float* qpre  = (float*)(ws + (32u << 20));                    // 8 MiB (reused as attno)
  unsigned short* qbf = (unsigned short*)(ws + (40u << 20));    // 4 MiB
  float* Mpart = (float*)(ws + (44u << 20));                    // 256 KiB
  float* Lpart = (float*)(ws + (44u << 20) + (256u << 10));     // 256 KiB
  unsigned long long* bits = (unsigned long long*)(ws + (44u << 20) + (512u << 10)); // 256 KiB
  float* costab = (float*)(ws + (45u << 20));
  float* sintab = costab + 256;
  int*   flags  = (int*)(sintab + 256);
  float* attno = qpre;                                          // qpre dead after rope

  prep_kernel<<<1, 256, 0, stream>>>((const int*)pos, (const unsigned int*)mask,
                                     costab, sintab, flags);
  maskpack_kernel<<<8192, 256, 0, stream>>>(mask, flags, bits);
  gemm_kernel<<<dim3(32, 8), 256, 0, stream>>>(hidden, wq, qpre, HIDD, HIDD);
  rope_kernel<<<4096, 256, 0, stream>>>(qpre, costab, sintab, qbf);
  attn_kernel<<<1024, 256, 0, stream>>>(qbf, kst, vst, bits, Opart, Mpart, Lpart);
  combine_kernel<<<8192, 256, 0, stream>>>(Opart, Mpart, Lpart, attno);
  gemm_kernel<<<dim3(32, 8), 256, 0, stream>>>(attno, wo, out, HIDD, HIDD);
}